// Round 7
// baseline (317.726 us; speedup 1.0000x reference)
//
#include <hip/hip_runtime.h>

// MultiScaleSubsequenceExtractor: masked sliding-window means.
// B=128, L=1024, D=128, windows {4,8,16,32}; out rows/batch = 1021+1017+1009+993 = 4040.
// Steady-state HBM/iter: ~64 MB read + 265 MB write -> ~52 us kernel floor at 6.3 TB/s.
// Ladder (kernel est. = bench - ~233 us fixed fill/graph overhead):
//  R2: LDS-stage TILE=64, NT loads + NT stores        ~80 us (bench 313)
//  R3: D-split 6 blocks/CU                             169 us (occupancy not the limiter)
//  R4: cached loads + PLAIN stores + swizzle           ~94 us (bench 327)
//  R5: no-LDS streaming                                ~148 us (latency-bound, dead)
//  R6: cached loads + NT stores                        ~74 us (bench 307.4) <- base
//  R7: 2-tile ring + reg prefetch (T14)                ~81 us (bench 314; reverted)
//  R8: global_load_lds staging + mask-at-read          ~76 us (bench 309.3; neutral,
//      staging round-trip was not the limiter -> reverted)
// R9: R6 exact + ISOLATED XCD-aware block swizzle (R4 ran it confounded with plain
//     stores). All 16 L-tiles of a batch-group land on one XCD -> the 32-row halo
//     (1/3 of each block's fetch) becomes an L2 hit instead of L3/HBM. Pure block
//     remap, bijective (2048 % 8 == 0); single variable vs the 307.4 baseline.

namespace {
constexpr int kB    = 128;
constexpr int kL    = 1024;
constexpr int kD    = 128;
constexpr int kD4   = kD / 4;        // float4 per row = 32
constexpr int TILE  = 64;            // output positions per block
constexpr int HALO  = 32;            // max window size
constexpr int ROWS  = TILE + HALO;   // 96 staged rows
constexpr int ROUT  = 4040;          // output rows per batch
constexpr int OFF4  = 0;
constexpr int OFF8  = 1021;
constexpr int OFF16 = 2038;          // 1021 + 1017
constexpr int OFF32 = 3047;          // 2038 + 1009
constexpr int NTILE = kL / TILE;     // 16 tiles along L
constexpr int NXCD  = 8;
constexpr int NBLK  = kB * NTILE;    // 2048 blocks
constexpr int CPX   = NBLK / NXCD;   // 256 logical blocks per XCD
}

typedef float v4f __attribute__((ext_vector_type(4)));

__device__ __forceinline__ void nt_store(float4* p, const float4& v) {
    v4f x;
    x.x = v.x; x.y = v.y; x.z = v.z; x.w = v.w;
    __builtin_nontemporal_store(x, reinterpret_cast<v4f*>(p));
}

__device__ __forceinline__ void acc4(float4& a, const float4& x) {
    a.x += x.x; a.y += x.y; a.z += x.z; a.w += x.w;
}
__device__ __forceinline__ void slide4(float4& a, const float4& xin, const float4& xout) {
    a.x += xin.x - xout.x; a.y += xin.y - xout.y;
    a.z += xin.z - xout.z; a.w += xin.w - xout.w;
}
__device__ __forceinline__ float4 scale4(const float4& v, float s) {
    return make_float4(v.x * s, v.y * s, v.z * s, v.w * s);
}

__global__ __launch_bounds__(256)
void msse_kernel(const float* __restrict__ emb,
                 const int*   __restrict__ mask,
                 float*       __restrict__ out) {
    __shared__ float4 s_data[ROWS * kD4];   // 48 KB: masked embeddings, row-major
    __shared__ float  s_mask[ROWS];
    __shared__ float  s_inv[4][TILE];       // 1/clip(count,1) per window per position

    // ---- XCD-aware swizzle: hw id h runs round-robin over 8 XCDs; logical id l gives
    //      each XCD a contiguous chunk of (b, tile) space with tile fastest, so the
    //      32-row halo shared by L-adjacent tiles is L2-resident on that XCD.
    const int hid  = blockIdx.x;                        // 0..2047
    const int l    = (hid & (NXCD - 1)) * CPX + (hid >> 3);
    const int tile = l & (NTILE - 1);
    const int b    = l >> 4;                            // NTILE = 16
    const int i0   = tile * TILE;
    const int t    = threadIdx.x;

    // ---- stage masked input tile (rows [i0, i0+96)) into LDS, float4 coalesced ----
    // CACHED loads (input can sit in L2/L3); NT stores below keep the 265 MB output
    // stream from cycling the caches. (R6's winning flavor combo — unchanged.)
    const float4* gsrc = reinterpret_cast<const float4*>(emb) + (size_t)b * kL * kD4;
    #pragma unroll
    for (int k = 0; k < (ROWS * kD4) / 256; ++k) {   // 3072/256 = 12 iters
        const int f    = t + k * 256;
        const int row  = f >> 5;                     // 32 float4 per row
        const int grow = i0 + row;
        float4 v = make_float4(0.f, 0.f, 0.f, 0.f);
        float  m = 0.f;
        if (grow < kL) {
            m = (float)mask[b * kL + grow];
            v = gsrc[(size_t)grow * kD4 + (f & 31)];
            v.x *= m; v.y *= m; v.z *= m; v.w *= m;
        }
        s_data[f] = v;
        if ((f & 31) == 0) s_mask[row] = m;
    }
    __syncthreads();

    // ---- per-position window-count reciprocals (threads 0..63) ----
    if (t < TILE) {
        float c = 0.f, c4 = 0.f, c8 = 0.f, c16 = 0.f;
        #pragma unroll
        for (int j = 0; j < 32; ++j) {
            c += s_mask[t + j];
            if (j == 3)  c4  = c;
            if (j == 7)  c8  = c;
            if (j == 15) c16 = c;
        }
        s_inv[0][t] = 1.f / fmaxf(c4,  1.f);
        s_inv[1][t] = 1.f / fmaxf(c8,  1.f);
        s_inv[2][t] = 1.f / fmaxf(c16, 1.f);
        s_inv[3][t] = 1.f / fmaxf(c,   1.f);
    }
    __syncthreads();

    // ---- sliding-window sums: thread = (float4 column, 8-position strip) ----
    const int lane  = t & 31;        // float4 column index
    const int strip = t >> 5;        // 0..7
    const int base  = strip * 8;     // first local position of strip

    const float4* col = s_data + lane;   // row stride = kD4

    float4 s4, s8, s16, s32;
    {
        float4 a  = make_float4(0.f, 0.f, 0.f, 0.f);
        float4 t4 = a, t8 = a, t16 = a;
        #pragma unroll
        for (int j = 0; j < 32; ++j) {
            acc4(a, col[(base + j) * kD4]);
            if (j == 3)  t4  = a;
            if (j == 7)  t8  = a;
            if (j == 15) t16 = a;
        }
        s4 = t4; s8 = t8; s16 = t16; s32 = a;
    }

    float4* outb = reinterpret_cast<float4*>(out) + (size_t)b * ROUT * kD4 + lane;

    #pragma unroll
    for (int p = 0; p < 8; ++p) {
        const int il = base + p;
        const int i  = i0 + il;

        if (i <= kL - 4)  nt_store(outb + (size_t)(OFF4  + i) * kD4, scale4(s4,  s_inv[0][il]));
        if (i <= kL - 8)  nt_store(outb + (size_t)(OFF8  + i) * kD4, scale4(s8,  s_inv[1][il]));
        if (i <= kL - 16) nt_store(outb + (size_t)(OFF16 + i) * kD4, scale4(s16, s_inv[2][il]));
        if (i <= kL - 32) nt_store(outb + (size_t)(OFF32 + i) * kD4, scale4(s32, s_inv[3][il]));

        // advance all windows to position i+1 (max row = base+7+32 = 95, in range)
        const float4 x0 = col[(il)      * kD4];
        const float4 xa = col[(il + 4)  * kD4];
        const float4 xb = col[(il + 8)  * kD4];
        const float4 xc = col[(il + 16) * kD4];
        const float4 xd = col[(il + 32) * kD4];
        slide4(s4,  xa, x0);
        slide4(s8,  xb, x0);
        slide4(s16, xc, x0);
        slide4(s32, xd, x0);
    }
}

extern "C" void kernel_launch(void* const* d_in, const int* in_sizes, int n_in,
                              void* d_out, int out_size, void* d_ws, size_t ws_size,
                              hipStream_t stream) {
    const float* emb  = (const float*)d_in[0];
    const int*   mask = (const int*)d_in[1];
    float*       out  = (float*)d_out;

    dim3 grid(NBLK);      // 2048 blocks = (128 b) x (16 L-tiles), XCD-swizzled
    dim3 block(256);
    msse_kernel<<<grid, block, 0, stream>>>(emb, mask, out);
}

// Round 8
// 308.392 us; speedup vs baseline: 1.0303x; 1.0303x over previous
//
#include <hip/hip_runtime.h>

// MultiScaleSubsequenceExtractor: masked sliding-window means.
// B=128, L=1024, D=128, windows {4,8,16,32}; out rows/batch = 1021+1017+1009+993 = 4040.
// Steady-state HBM/iter: ~64 MB read + 265 MB write -> ~52 us kernel floor at 6.3 TB/s.
// Ladder (kernel est. = bench - ~233 us fixed fill/graph overhead; R3/R5 anchor it):
//  R2: LDS-stage TILE=64, NT loads + NT stores        ~80 us (bench 313.2)
//  R3: D-split 6 blocks/CU                             169 us (occupancy not the limiter)
//  R4: cached loads + PLAIN stores + swizzle           ~94 us (bench 326.8)
//  R5: no-LDS streaming, 5 global taps/pos            ~148 us (bench 381.0; latency-bound)
//  R6: cached loads + NT stores                        ~74 us (bench 307.4) <- BEST
//  R7: 2-tile ring + reg prefetch (T14)                ~81 us (bench 314.2; ring VALU ate it)
//  R8: global_load_lds staging + mask-at-read          ~76 us (bench 309.3; neutral)
//  R9: R6 + isolated XCD swizzle                       ~85 us (bench 317.7; REGRESSION —
//      no panel-sharing between blocks; swizzle serializes a batch's reads on one XCD)
// R10: byte-exact revert to R6 (A/A reproduction of the best point).
// Surviving theory of the residual ~22 us: stage->barrier->compute phase latency at
// 3 blocks/CU; its removal was refuted three independent ways (R5, R7, R8).

namespace {
constexpr int kB    = 128;
constexpr int kL    = 1024;
constexpr int kD    = 128;
constexpr int kD4   = kD / 4;        // float4 per row = 32
constexpr int TILE  = 64;            // output positions per block
constexpr int HALO  = 32;            // max window size
constexpr int ROWS  = TILE + HALO;   // 96 staged rows
constexpr int ROUT  = 4040;          // output rows per batch
constexpr int OFF4  = 0;
constexpr int OFF8  = 1021;
constexpr int OFF16 = 2038;          // 1021 + 1017
constexpr int OFF32 = 3047;          // 2038 + 1009
}

typedef float v4f __attribute__((ext_vector_type(4)));

__device__ __forceinline__ void nt_store(float4* p, const float4& v) {
    v4f x;
    x.x = v.x; x.y = v.y; x.z = v.z; x.w = v.w;
    __builtin_nontemporal_store(x, reinterpret_cast<v4f*>(p));
}

__device__ __forceinline__ void acc4(float4& a, const float4& x) {
    a.x += x.x; a.y += x.y; a.z += x.z; a.w += x.w;
}
__device__ __forceinline__ void slide4(float4& a, const float4& xin, const float4& xout) {
    a.x += xin.x - xout.x; a.y += xin.y - xout.y;
    a.z += xin.z - xout.z; a.w += xin.w - xout.w;
}
__device__ __forceinline__ float4 scale4(const float4& v, float s) {
    return make_float4(v.x * s, v.y * s, v.z * s, v.w * s);
}

__global__ __launch_bounds__(256)
void msse_kernel(const float* __restrict__ emb,
                 const int*   __restrict__ mask,
                 float*       __restrict__ out) {
    __shared__ float4 s_data[ROWS * kD4];   // 48 KB: masked embeddings, row-major
    __shared__ float  s_mask[ROWS];
    __shared__ float  s_inv[4][TILE];       // 1/clip(count,1) per window per position

    const int b  = blockIdx.y;
    const int i0 = blockIdx.x * TILE;
    const int t  = threadIdx.x;

    // ---- stage masked input tile (rows [i0, i0+96)) into LDS, float4 coalesced ----
    // CACHED loads (input can sit in L2/L3); NT stores below keep the 265 MB output
    // stream from cycling the caches. (The measured-best flavor combo.)
    const float4* gsrc = reinterpret_cast<const float4*>(emb) + (size_t)b * kL * kD4;
    #pragma unroll
    for (int k = 0; k < (ROWS * kD4) / 256; ++k) {   // 3072/256 = 12 iters
        const int f    = t + k * 256;
        const int row  = f >> 5;                     // 32 float4 per row
        const int grow = i0 + row;
        float4 v = make_float4(0.f, 0.f, 0.f, 0.f);
        float  m = 0.f;
        if (grow < kL) {
            m = (float)mask[b * kL + grow];
            v = gsrc[(size_t)grow * kD4 + (f & 31)];
            v.x *= m; v.y *= m; v.z *= m; v.w *= m;
        }
        s_data[f] = v;
        if ((f & 31) == 0) s_mask[row] = m;
    }
    __syncthreads();

    // ---- per-position window-count reciprocals (threads 0..63) ----
    if (t < TILE) {
        float c = 0.f, c4 = 0.f, c8 = 0.f, c16 = 0.f;
        #pragma unroll
        for (int j = 0; j < 32; ++j) {
            c += s_mask[t + j];
            if (j == 3)  c4  = c;
            if (j == 7)  c8  = c;
            if (j == 15) c16 = c;
        }
        s_inv[0][t] = 1.f / fmaxf(c4,  1.f);
        s_inv[1][t] = 1.f / fmaxf(c8,  1.f);
        s_inv[2][t] = 1.f / fmaxf(c16, 1.f);
        s_inv[3][t] = 1.f / fmaxf(c,   1.f);
    }
    __syncthreads();

    // ---- sliding-window sums: thread = (float4 column, 8-position strip) ----
    const int lane  = t & 31;        // float4 column index
    const int strip = t >> 5;        // 0..7
    const int base  = strip * 8;     // first local position of strip

    const float4* col = s_data + lane;   // row stride = kD4

    float4 s4, s8, s16, s32;
    {
        float4 a  = make_float4(0.f, 0.f, 0.f, 0.f);
        float4 t4 = a, t8 = a, t16 = a;
        #pragma unroll
        for (int j = 0; j < 32; ++j) {
            acc4(a, col[(base + j) * kD4]);
            if (j == 3)  t4  = a;
            if (j == 7)  t8  = a;
            if (j == 15) t16 = a;
        }
        s4 = t4; s8 = t8; s16 = t16; s32 = a;
    }

    float4* outb = reinterpret_cast<float4*>(out) + (size_t)b * ROUT * kD4 + lane;

    #pragma unroll
    for (int p = 0; p < 8; ++p) {
        const int il = base + p;
        const int i  = i0 + il;

        if (i <= kL - 4)  nt_store(outb + (size_t)(OFF4  + i) * kD4, scale4(s4,  s_inv[0][il]));
        if (i <= kL - 8)  nt_store(outb + (size_t)(OFF8  + i) * kD4, scale4(s8,  s_inv[1][il]));
        if (i <= kL - 16) nt_store(outb + (size_t)(OFF16 + i) * kD4, scale4(s16, s_inv[2][il]));
        if (i <= kL - 32) nt_store(outb + (size_t)(OFF32 + i) * kD4, scale4(s32, s_inv[3][il]));

        // advance all windows to position i+1 (max row = base+7+32 = 95, in range)
        const float4 x0 = col[(il)      * kD4];
        const float4 xa = col[(il + 4)  * kD4];
        const float4 xb = col[(il + 8)  * kD4];
        const float4 xc = col[(il + 16) * kD4];
        const float4 xd = col[(il + 32) * kD4];
        slide4(s4,  xa, x0);
        slide4(s8,  xb, x0);
        slide4(s16, xc, x0);
        slide4(s32, xd, x0);
    }
}

extern "C" void kernel_launch(void* const* d_in, const int* in_sizes, int n_in,
                              void* d_out, int out_size, void* d_ws, size_t ws_size,
                              hipStream_t stream) {
    const float* emb  = (const float*)d_in[0];
    const int*   mask = (const int*)d_in[1];
    float*       out  = (float*)d_out;

    dim3 grid((kL + TILE - 1) / TILE, kB);   // (16, 128) = 2048 blocks
    dim3 block(256);
    msse_kernel<<<grid, block, 0, stream>>>(emb, mask, out);
}